// Round 5
// baseline (6849.432 us; speedup 1.0000x reference)
//
#include <hip/hip_runtime.h>
#include <hip/hip_bf16.h>

#define SDIM 512
#define BDIM 64
#define INDIM 512
#define HDIM 1024
#define OUTDIM 512
#define NWG 256
#define THREADS 512
#define BH (BDIM * HDIM)

typedef __bf16 bfreg;
typedef bfreg bf16x8 __attribute__((ext_vector_type(8)));
typedef bfreg bf16x4 __attribute__((ext_vector_type(4)));
typedef float f32x4 __attribute__((ext_vector_type(4)));
typedef unsigned int u32x4 __attribute__((ext_vector_type(4)));

__device__ __forceinline__ float sigf(float x) { return 1.f / (1.f + __expf(-x)); }
__device__ __forceinline__ float tanhfast(float x) { return 1.f - 2.f / (__expf(2.f * x) + 1.f); }

// ---------- preamble kernels ----------

__global__ void cvt_bf16(bfreg* __restrict__ dst, const float* __restrict__ src, int n4)
{
    for (int i = blockIdx.x * blockDim.x + threadIdx.x; i < n4; i += gridDim.x * blockDim.x) {
        const float4 v = *(const float4*)(src + (size_t)i * 4);
        bf16x4 o;
        o[0] = (bfreg)v.x; o[1] = (bfreg)v.y; o[2] = (bfreg)v.z; o[3] = (bfreg)v.w;
        *(bf16x4*)(dst + (size_t)i * 4) = o;
    }
}

__global__ void bias_combine(float* __restrict__ b0, const float* __restrict__ bx0,
                             const float* __restrict__ bh0,
                             float* __restrict__ b1, const float* __restrict__ bx1,
                             const float* __restrict__ bh1)
{
    int i = blockIdx.x * blockDim.x + threadIdx.x;
    if (i < 4 * HDIM) {
        b0[i] = bx0[i] + bh0[i];
        b1[i] = bx1[i] + bh1[i];
    }
}

// Pack x [S][B][IN] fp32 -> chunked bf16 [S][IN/8][B][8]
__global__ void pack_x(bfreg* __restrict__ dst, const float* __restrict__ src)
{
    const int total = SDIM * (INDIM / 8) * BDIM;      // 16B chunks
    for (int idx = blockIdx.x * blockDim.x + threadIdx.x; idx < total;
         idx += gridDim.x * blockDim.x) {
        const int b = idx & (BDIM - 1);
        const int r = idx >> 6;
        const int kb = r & (INDIM / 8 - 1);
        const int t = r >> 6;
        const float* s = src + ((size_t)t * BDIM + b) * INDIM + kb * 8;
        bfreg* d = dst + (size_t)idx * 8;
        #pragma unroll
        for (int j = 0; j < 8; ++j) d[j] = (bfreg)s[j];
    }
}

// Pack W = [Wx | Uh] (row-major fp32) into per-WG MFMA B-fragment order, bf16.
// dst chunk idx = ((wg*2 + nt)*KST + ks)*64 + lane ; each chunk = 8 bf16.
// rr = nt*16 + (lane&15); g = rr>>3, uo = rr&7; row = g*HDIM + wg*8 + uo;
// k = ks*32 + (lane>>4)*8 + j.
__global__ void pack_w(bfreg* __restrict__ dst, const float* __restrict__ Wx,
                       const float* __restrict__ Uh, int K0, int KH)
{
    const int KST = (K0 + KH) / 32;
    const int total = 128 * 2 * KST * 64;
    for (int idx = blockIdx.x * blockDim.x + threadIdx.x; idx < total;
         idx += gridDim.x * blockDim.x) {
        const int lane = idx & 63;
        int rem = idx >> 6;
        const int ks = rem % KST; rem /= KST;
        const int nt = rem & 1;
        const int wg = rem >> 1;
        const int rr = nt * 16 + (lane & 15);
        const int g = rr >> 3, uo = rr & 7;
        const int row = g * HDIM + wg * 8 + uo;
        const int k = ks * 32 + (lane >> 4) * 8;
        const float* s = (k < K0) ? Wx + (size_t)row * K0 + k
                                  : Uh + (size_t)row * KH + (k - K0);
        bfreg* d = dst + (size_t)idx * 8;
        #pragma unroll
        for (int j = 0; j < 8; ++j) d[j] = (bfreg)s[j];
    }
}

// ---------- flag helpers ----------

__device__ __forceinline__ void wait_flags(const unsigned* f, int lane)
{
    const unsigned long long* p = (const unsigned long long*)f + lane;
    const unsigned long long EXP = 0x0000000100000001ull;
    while (true) {
        unsigned long long v = __hip_atomic_load(p, __ATOMIC_RELAXED, __HIP_MEMORY_SCOPE_AGENT);
        if (__all(v == EXP)) break;
    }
}

__device__ __forceinline__ void lds_spin(int* r, int target)
{
    while (__hip_atomic_load(r, __ATOMIC_ACQUIRE, __HIP_MEMORY_SCOPE_WORKGROUP) < target)
        __builtin_amdgcn_s_sleep(1);
}

// ---------- persistent 2-layer LSTM scan (flag-pipelined, dependency-exact) ----------
// 256 WGs x 512 threads, 1 WG/CU. layer = wgid&1, rg = wgid>>1 (8 h-units).
// Waves: wid = (xh<<2)|m ; xh = DEPENDENCY CLASS, m = 16-row batch tile.
//   L0: xh=0 -> ks[0,16)  = Wx*x[t]       : NO flag wait (x is preamble data)
//       xh=1 -> ks[16,48) = Uh*h0[t-1]    : waits flag0[t-1] (poller wave 4)
//   L1: xh=0 -> ks[0,32)  = Wx*h0[t]      : waits flag0[t]   (poller wave 0)
//       xh=1 -> ks[32,64) = Uh*h1[t-1]    : waits flag1[t-1] (poller wave 4)
// Pollers do tight agent-scope flag polls (no sleep); other waves of the class
// spin on an LDS ready counter. gatebuf halves = {x-half, h-half}, summed in
// the epilogue. Publish = wave 0: 1KB slice 16B/lane sc0 sc1 write-through,
// vmcnt(0), then lane0 stores this WG's per-step flag.
__global__ __launch_bounds__(THREADS, 1)
void lstm_scan(const bfreg* __restrict__ Pw0, const bfreg* __restrict__ Pw1,
               const float* __restrict__ bias0, const float* __restrict__ bias1,
               const bfreg* __restrict__ x_pk,
               bfreg* __restrict__ Hb0, bfreg* __restrict__ Hb1,
               unsigned* __restrict__ flag0, unsigned* __restrict__ flag1)
{
    extern __shared__ char smem[];
    const int wgid = blockIdx.x;
    const int layer = wgid & 1;
    const int rg = wgid >> 1;
    const int tid = threadIdx.x;
    const int l = tid & 63;
    const int wid = tid >> 6;
    const int m = wid & 3;          // m-tile (16 batch rows)
    const int xh = wid >> 2;        // dependency class

    const int KST = layer ? 64 : 48;
    const size_t WELEM = (size_t)KST * 1024;

    bfreg* lW = (bfreg*)smem;
    float* gatebuf = (float*)(smem + 64 * 2048);   // [2][32][68] f32 (fixed offset)
    float* cbuf = gatebuf + 2 * 32 * 68;           // [8][68]
    float* lbias = cbuf + 8 * 68;                  // [32]
    unsigned short* hbuf = (unsigned short*)(lbias + 32);  // [64][8] bf16
    int* ready = (int*)(hbuf + 64 * 8);            // [2] step counters

    // stage packed weights (once)
    {
        const float4* wsrc = (const float4*)((layer ? Pw1 : Pw0) + (size_t)rg * WELEM);
        float4* wdst = (float4*)lW;
        const int n16 = KST * 128;
        for (int i = tid; i < n16; i += THREADS) wdst[i] = wsrc[i];
    }
    if (tid < 32) {
        const int g = tid >> 3, uo = tid & 7;
        lbias[tid] = (layer ? bias1 : bias0)[g * HDIM + rg * 8 + uo];
    }
    if (tid < 2) ready[tid] = 0;
    for (int i = tid; i < 8 * 68; i += THREADS) cbuf[i] = 0.f;
    __syncthreads();

    const int cl = l & 15, kg = l >> 4;
    const int rowA = m * 16 + cl;
    int ks_beg, ks_end;
    if (!layer) { ks_beg = xh ? 16 : 0; ks_end = xh ? 48 : 16; }
    else        { ks_beg = xh * 32;     ks_end = ks_beg + 32;  }
    const int KB0 = layer ? 128 : 64;              // chunks in src0

    unsigned* myflag = (layer ? flag1 : flag0) + rg;
    bfreg* Hme = layer ? Hb1 : Hb0;

    for (int t = 0; t < SDIM; ++t) {
        // ---- dependency wait: poller waves hit LLC, classmates spin on LDS ----
        if (!layer) {
            if (xh == 1 && t > 0) {
                if (wid == 4) {
                    wait_flags(flag0 + (size_t)(t - 1) * 128, l);
                    __hip_atomic_store(&ready[0], t, __ATOMIC_RELEASE,
                                       __HIP_MEMORY_SCOPE_WORKGROUP);
                } else {
                    lds_spin(&ready[0], t);
                }
            }
            // xh==0: x-only, never waits
        } else {
            if (xh == 0) {             // needs h0[t]
                if (wid == 0) {
                    wait_flags(flag0 + (size_t)t * 128, l);
                    __hip_atomic_store(&ready[0], t + 1, __ATOMIC_RELEASE,
                                       __HIP_MEMORY_SCOPE_WORKGROUP);
                } else {
                    lds_spin(&ready[0], t + 1);
                }
            } else if (t > 0) {        // needs h1[t-1]
                if (wid == 4) {
                    wait_flags(flag1 + (size_t)(t - 1) * 128, l);
                    __hip_atomic_store(&ready[1], t, __ATOMIC_RELEASE,
                                       __HIP_MEMORY_SCOPE_WORKGROUP);
                } else {
                    lds_spin(&ready[1], t);
                }
            }
        }
        asm volatile("" ::: "memory");

        const bfreg* s0 = layer ? Hb0 + (size_t)(t + 1) * BH
                                : x_pk + (size_t)t * (64 * BDIM * 8);
        const bfreg* s1 = layer ? Hb1 + (size_t)t * BH
                                : Hb0 + (size_t)t * BH;

        f32x4 acc0 = {0.f, 0.f, 0.f, 0.f};
        f32x4 acc1 = {0.f, 0.f, 0.f, 0.f};
        #pragma unroll 8
        for (int ks = ks_beg; ks < ks_end; ++ks) {
            const int cb = ks * 4 + kg;
            const bfreg* ap = (cb < KB0) ? s0 + (size_t)cb * 512 + rowA * 8
                                         : s1 + (size_t)(cb - KB0) * 512 + rowA * 8;
            const bf16x8 a = *(const bf16x8*)ap;
            const bf16x8 w0 = *(const bf16x8*)(lW + ((size_t)ks * 64 + l) * 8);
            const bf16x8 w1 = *(const bf16x8*)(lW + ((size_t)(KST + ks) * 64 + l) * 8);
            acc0 = __builtin_amdgcn_mfma_f32_16x16x32_bf16(a, w0, acc0, 0, 0, 0);
            acc1 = __builtin_amdgcn_mfma_f32_16x16x32_bf16(a, w1, acc1, 0, 0, 0);
        }
        // C/D: col(rr in ntile) = l&15 ; row(batch) = m*16 + (l>>4)*4 + r
        float* gb = gatebuf + xh * (32 * 68);
        const int bb = m * 16 + (l >> 4) * 4;
        *(f32x4*)(gb + (0 * 16 + cl) * 68 + bb) = acc0;
        *(f32x4*)(gb + (1 * 16 + cl) * 68 + bb) = acc1;
        __syncthreads();   // [A] gates ready

        // ---- epilogue: thread -> (uo = tid&7, b = tid>>3) ----
        {
            const int uo = tid & 7, b = tid >> 3;
            float* g0 = gatebuf;
            float* g1 = gatebuf + 32 * 68;
            const float fv = g0[uo * 68 + b]        + g1[uo * 68 + b]        + lbias[uo];
            const float iv = g0[(8 + uo) * 68 + b]  + g1[(8 + uo) * 68 + b]  + lbias[8 + uo];
            const float ov = g0[(16 + uo) * 68 + b] + g1[(16 + uo) * 68 + b] + lbias[16 + uo];
            const float gv = g0[(24 + uo) * 68 + b] + g1[(24 + uo) * 68 + b] + lbias[24 + uo];
            const float c = cbuf[uo * 68 + b];
            const float fg = sigf(fv), ig = sigf(iv), og = sigf(ov);
            const float gg = tanhfast(gv);
            const float cn = fg * c + ig * gg;
            cbuf[uo * 68 + b] = cn;
            const bfreg hv = (bfreg)(og * tanhfast(cn));
            hbuf[b * 8 + uo] = *(const unsigned short*)&hv;
        }
        __syncthreads();   // [B] hbuf ready

        // ---- publish: wave 0 stores 1KB slice (16B/lane) + flag ----
        if (wid == 0) {
            const u32x4 val = ((const u32x4*)hbuf)[l];
            bfreg* dp = Hme + (size_t)(t + 1) * BH + rg * 512 + l * 8;
            asm volatile("global_store_dwordx4 %0, %1, off sc0 sc1"
                         :: "v"(dp), "v"(val) : "memory");
            asm volatile("s_waitcnt vmcnt(0)" ::: "memory");
            if (l == 0) {
                unsigned* fp = myflag + (size_t)t * 128;
                const unsigned one = 1u;
                asm volatile("global_store_dword %0, %1, off sc0 sc1"
                             :: "v"(fp), "v"(one) : "memory");
            }
        }
        // no WG-wide barrier after publish: gatebuf(t+1) writes only happen
        // after [B](t); hbuf(t+1) writes only after [A](t+1).
    }
}

// ---------- FC head ----------
// A = Hb1 slots 1..512 in chunked layout; Wb row-major [OUT][HDIM]
__global__ void fc_gemm(const bfreg* __restrict__ Hb1, const bfreg* __restrict__ Wb,
                        const float* __restrict__ bias, float* __restrict__ out)
{
    const int lane = threadIdx.x & 63;
    const int wid = threadIdx.x >> 6;
    const int cl = lane & 15, kg = lane >> 4;
    const int mbase = blockIdx.y * 64 + (wid >> 1) * 32;
    const int nbase = blockIdx.x * 64 + (wid & 1) * 32;
    const int t = mbase >> 6;
    const int b0 = mbase & 63;
    const bfreg* pa0 = Hb1 + (size_t)(t + 1) * BH + (size_t)kg * 512 + (b0 + cl) * 8;
    const bfreg* pa1 = pa0 + 16 * 8;
    const bfreg* pb0 = Wb + (size_t)(nbase + cl) * HDIM + kg * 8;
    const bfreg* pb1 = pb0 + (size_t)16 * HDIM;
    f32x4 acc[2][2] = {};
    #pragma unroll 4
    for (int k = 0; k < HDIM; k += 32) {
        const size_t co = (size_t)(k >> 3) * 512;
        const bf16x8 av0 = *(const bf16x8*)(pa0 + co);
        const bf16x8 av1 = *(const bf16x8*)(pa1 + co);
        const bf16x8 bv0 = *(const bf16x8*)(pb0 + k);
        const bf16x8 bv1 = *(const bf16x8*)(pb1 + k);
        acc[0][0] = __builtin_amdgcn_mfma_f32_16x16x32_bf16(av0, bv0, acc[0][0], 0, 0, 0);
        acc[0][1] = __builtin_amdgcn_mfma_f32_16x16x32_bf16(av0, bv1, acc[0][1], 0, 0, 0);
        acc[1][0] = __builtin_amdgcn_mfma_f32_16x16x32_bf16(av1, bv0, acc[1][0], 0, 0, 0);
        acc[1][1] = __builtin_amdgcn_mfma_f32_16x16x32_bf16(av1, bv1, acc[1][1], 0, 0, 0);
    }
    #pragma unroll
    for (int mi = 0; mi < 2; ++mi)
        #pragma unroll
        for (int ni = 0; ni < 2; ++ni)
            #pragma unroll
            for (int r = 0; r < 4; ++r) {
                const int row = mbase + mi * 16 + kg * 4 + r;
                const int col = nbase + ni * 16 + cl;
                out[(size_t)row * OUTDIM + col] = acc[mi][ni][r] + bias[col];
            }
}

extern "C" void kernel_launch(void* const* d_in, const int* in_sizes, int n_in,
                              void* d_out, int out_size, void* d_ws, size_t ws_size,
                              hipStream_t stream)
{
    const float* x     = (const float*)d_in[0];
    const float* l0_Wx = (const float*)d_in[1];
    const float* l0_Uh = (const float*)d_in[2];
    const float* l0_bx = (const float*)d_in[3];
    const float* l0_bh = (const float*)d_in[4];
    const float* l1_Wx = (const float*)d_in[5];
    const float* l1_Uh = (const float*)d_in[6];
    const float* l1_bx = (const float*)d_in[7];
    const float* l1_bh = (const float*)d_in[8];
    const float* fc_W  = (const float*)d_in[9];
    const float* fc_b  = (const float*)d_in[10];
    (void)in_sizes; (void)n_in; (void)out_size; (void)ws_size;

    char* p = (char*)d_ws;
    size_t off = 0;
    auto take = [&](size_t bytes) {
        void* r = p + off;
        off = (off + bytes + 255) & ~(size_t)255;
        return r;
    };

    bfreg* x_pk  = (bfreg*)take((size_t)SDIM * BDIM * INDIM * 2);
    bfreg* Pw0   = (bfreg*)take((size_t)128 * 48 * 1024 * 2);
    bfreg* Pw1   = (bfreg*)take((size_t)128 * 64 * 1024 * 2);
    bfreg* fcWb  = (bfreg*)take((size_t)OUTDIM * HDIM * 2);
    float* bias0 = (float*)take((size_t)4 * HDIM * 4);
    float* bias1 = (float*)take((size_t)4 * HDIM * 4);
    bfreg* Hb0   = (bfreg*)take((size_t)(SDIM + 1) * BH * 2);
    bfreg* Hb1   = (bfreg*)take((size_t)(SDIM + 1) * BH * 2);
    unsigned* flag0 = (unsigned*)take((size_t)SDIM * 128 * 4);
    unsigned* flag1 = (unsigned*)take((size_t)SDIM * 128 * 4);

    // deterministic per-call init (graph-replayed)
    hipMemsetAsync(Hb0, 0, (size_t)BH * 2, stream);
    hipMemsetAsync(Hb1, 0, (size_t)BH * 2, stream);
    hipMemsetAsync(flag0, 0, (size_t)SDIM * 128 * 4, stream);
    hipMemsetAsync(flag1, 0, (size_t)SDIM * 128 * 4, stream);

    pack_x<<<4096, 256, 0, stream>>>(x_pk, x);
    cvt_bf16<<<512, 256, 0, stream>>>(fcWb, fc_W, OUTDIM * HDIM / 4);
    pack_w<<<3072, 256, 0, stream>>>(Pw0, l0_Wx, l0_Uh, INDIM, HDIM);
    pack_w<<<4096, 256, 0, stream>>>(Pw1, l1_Wx, l1_Uh, HDIM, HDIM);
    bias_combine<<<16, 256, 0, stream>>>(bias0, l0_bx, l0_bh, bias1, l1_bx, l1_bh);

    const int smem_bytes = 64 * 2048 + 2 * 32 * 68 * 4 + 8 * 68 * 4 + 32 * 4
                         + 64 * 8 * 2 + 16;
    hipFuncSetAttribute((const void*)lstm_scan,
                        hipFuncAttributeMaxDynamicSharedMemorySize, smem_bytes);
    lstm_scan<<<NWG, THREADS, smem_bytes, stream>>>(Pw0, Pw1, bias0, bias1,
                                                    x_pk, Hb0, Hb1, flag0, flag1);

    fc_gemm<<<dim3(OUTDIM / 64, SDIM * BDIM / 64), 256, 0, stream>>>(
        Hb1, fcWb, fc_b, (float*)d_out);
}

// Round 6
// 4498.767 us; speedup vs baseline: 1.5225x; 1.5225x over previous
//
#include <hip/hip_runtime.h>
#include <hip/hip_bf16.h>

#define SDIM 512
#define BDIM 64
#define INDIM 512
#define HDIM 1024
#define OUTDIM 512
#define NWG 256
#define THREADS 512
#define BH (BDIM * HDIM)

typedef __bf16 bfreg;
typedef bfreg bf16x8 __attribute__((ext_vector_type(8)));
typedef bfreg bf16x4 __attribute__((ext_vector_type(4)));
typedef float f32x4 __attribute__((ext_vector_type(4)));

__device__ __forceinline__ float sigf(float x) { return 1.f / (1.f + __expf(-x)); }
__device__ __forceinline__ float tanhfast(float x) { return 1.f - 2.f / (__expf(2.f * x) + 1.f); }

// ---------- preamble kernels ----------

__global__ void cvt_bf16(bfreg* __restrict__ dst, const float* __restrict__ src, int n4)
{
    for (int i = blockIdx.x * blockDim.x + threadIdx.x; i < n4; i += gridDim.x * blockDim.x) {
        const float4 v = *(const float4*)(src + (size_t)i * 4);
        bf16x4 o;
        o[0] = (bfreg)v.x; o[1] = (bfreg)v.y; o[2] = (bfreg)v.z; o[3] = (bfreg)v.w;
        *(bf16x4*)(dst + (size_t)i * 4) = o;
    }
}

__global__ void bias_combine(float* __restrict__ b0, const float* __restrict__ bx0,
                             const float* __restrict__ bh0,
                             float* __restrict__ b1, const float* __restrict__ bx1,
                             const float* __restrict__ bh1)
{
    int i = blockIdx.x * blockDim.x + threadIdx.x;
    if (i < 4 * HDIM) {
        b0[i] = bx0[i] + bh0[i];
        b1[i] = bx1[i] + bh1[i];
    }
}

// Pack x [S][B][IN] fp32 -> chunked bf16 [S][IN/8][B][8]
__global__ void pack_x(bfreg* __restrict__ dst, const float* __restrict__ src)
{
    const int total = SDIM * (INDIM / 8) * BDIM;      // 16B chunks
    for (int idx = blockIdx.x * blockDim.x + threadIdx.x; idx < total;
         idx += gridDim.x * blockDim.x) {
        const int b = idx & (BDIM - 1);
        const int r = idx >> 6;
        const int kb = r & (INDIM / 8 - 1);
        const int t = r >> 6;
        const float* s = src + ((size_t)t * BDIM + b) * INDIM + kb * 8;
        bfreg* d = dst + (size_t)idx * 8;
        #pragma unroll
        for (int j = 0; j < 8; ++j) d[j] = (bfreg)s[j];
    }
}

// Pack W = [Wx | Uh] (row-major fp32) into per-WG MFMA B-fragment order, bf16.
// dst chunk idx = ((wg*2 + nt)*KST + ks)*64 + lane ; each chunk = 8 bf16.
// rr = nt*16 + (lane&15); g = rr>>3, uo = rr&7; row = g*HDIM + wg*8 + uo;
// k = ks*32 + (lane>>4)*8 + j.
__global__ void pack_w(bfreg* __restrict__ dst, const float* __restrict__ Wx,
                       const float* __restrict__ Uh, int K0, int KH)
{
    const int KST = (K0 + KH) / 32;
    const int total = 128 * 2 * KST * 64;
    for (int idx = blockIdx.x * blockDim.x + threadIdx.x; idx < total;
         idx += gridDim.x * blockDim.x) {
        const int lane = idx & 63;
        int rem = idx >> 6;
        const int ks = rem % KST; rem /= KST;
        const int nt = rem & 1;
        const int wg = rem >> 1;
        const int rr = nt * 16 + (lane & 15);
        const int g = rr >> 3, uo = rr & 7;
        const int row = g * HDIM + wg * 8 + uo;
        const int k = ks * 32 + (lane >> 4) * 8;
        const float* s = (k < K0) ? Wx + (size_t)row * K0 + k
                                  : Uh + (size_t)row * KH + (k - K0);
        bfreg* d = dst + (size_t)idx * 8;
        #pragma unroll
        for (int j = 0; j < 8; ++j) d[j] = (bfreg)s[j];
    }
}

// ---------- flag helpers ----------

__device__ __forceinline__ void wait_flags(const unsigned* f, int lane)
{
    const unsigned long long* p = (const unsigned long long*)f + lane;
    const unsigned long long EXP = 0x0000000100000001ull;
    while (true) {
        unsigned long long v = __hip_atomic_load(p, __ATOMIC_RELAXED, __HIP_MEMORY_SCOPE_AGENT);
        if (__all(v == EXP)) break;
        __builtin_amdgcn_s_sleep(1);
    }
}

__device__ __forceinline__ void lds_spin(int* r, int target)
{
    while (__hip_atomic_load(r, __ATOMIC_ACQUIRE, __HIP_MEMORY_SCOPE_WORKGROUP) < target)
        __builtin_amdgcn_s_sleep(1);
}

// ---------- persistent 2-layer LSTM scan: two-phase waves ----------
// 256 WGs x 512 threads, 1 WG/CU. layer = wgid&1, rg = wgid>>1 (8 h-units,
// 32 gate rows). Waves: wid = (kh<<2)|m ; m = 16-row batch tile, kh = K-half
// of EACH phase. Per step each wave does:
//   EARLY (weak/no gate):  L0: x chunks        L1: Uh1*h1[t-1]   (16/8 iters)
//   LATE  (flag-gated):    L0: Uh0*h0[t-1]     L1: Wx1*h0[t]     (16 iters)
// accumulated into the same registers; late A-frags preloaded 16-deep.
// Pollers: wave0 = late gate; wave4 = L1 early gate; wave1 = flag publisher
// (spins LDS done counter, then stores this WG's per-step flag).
// Publish: epilogue thread tid holds slice element tid -> per-wave 2B/lane
// coalesced sc0sc1 stores + per-wave vmcnt(0) + done+=1.
template<int LAYER>
__device__ __forceinline__ void scan_layer(
    const bfreg* __restrict__ Pw, const float* __restrict__ biasL,
    const bfreg* __restrict__ x_pk,
    bfreg* __restrict__ Hb0, bfreg* __restrict__ Hb1,
    unsigned* __restrict__ flag0, unsigned* __restrict__ flag1,
    const int rg, char* smem)
{
    constexpr int KST = LAYER ? 64 : 48;
    constexpr int ECNT = LAYER ? 16 : 8;
    constexpr int LCNT = 16;
    constexpr int KB0 = LAYER ? 128 : 64;     // chunks in s0

    const int tid = threadIdx.x;
    const int l = tid & 63;
    const int wid = tid >> 6;
    const int m = wid & 3;
    const int kh = wid >> 2;

    bfreg* lW = (bfreg*)smem;
    float* gatebuf = (float*)(smem + 64 * 2048);   // [2][32][68]
    float* cbuf = gatebuf + 2 * 32 * 68;           // [8][68]
    float* lbias = cbuf + 8 * 68;                  // [32]
    int* ready = (int*)(lbias + 32);               // [0],[1] gates, [2] done

    // stage packed weights (once)
    {
        const float4* wsrc = (const float4*)(Pw + (size_t)rg * ((size_t)KST * 1024));
        float4* wdst = (float4*)lW;
        for (int i = tid; i < KST * 128; i += THREADS) wdst[i] = wsrc[i];
    }
    if (tid < 32) lbias[tid] = biasL[(tid >> 3) * HDIM + rg * 8 + (tid & 7)];
    if (tid < 3) ready[tid] = 0;
    for (int i = tid; i < 8 * 68; i += THREADS) cbuf[i] = 0.f;
    __syncthreads();

    const int cl = l & 15, kg = l >> 4;
    const int rowA = m * 16 + cl;
    const int e_beg = LAYER ? (32 + kh * 16) : (kh * 8);
    const int l_beg = LAYER ? (kh * 16) : (16 + kh * 16);

    unsigned* myflag = (LAYER ? flag1 : flag0) + rg;
    bfreg* Hme = LAYER ? Hb1 : Hb0;
    int* done = ready + 2;

    for (int t = 0; t < SDIM; ++t) {
        // ---- early gate (L1 only): flag1[t-1], poller = wave 4 ----
        if (LAYER && t > 0) {
            if (wid == 4) {
                wait_flags(flag1 + (size_t)(t - 1) * 128, l);
                __hip_atomic_store(&ready[1], t, __ATOMIC_RELEASE,
                                   __HIP_MEMORY_SCOPE_WORKGROUP);
            } else {
                lds_spin(&ready[1], t);
            }
        }
        asm volatile("" ::: "memory");

        const bfreg* s0 = LAYER ? Hb0 + (size_t)(t + 1) * BH
                                : x_pk + (size_t)t * (64 * BDIM * 8);
        const bfreg* s1 = LAYER ? Hb1 + (size_t)t * BH
                                : Hb0 + (size_t)t * BH;

        f32x4 acc0 = {0.f, 0.f, 0.f, 0.f};
        f32x4 acc1 = {0.f, 0.f, 0.f, 0.f};

        // ---- early phase: L0 = Wx*x[t] (no gate), L1 = Uh*h1[t-1] ----
        {
            const bfreg* ebase = LAYER ? s1 : s0;     // L1 early: cb-128 ; L0: cb
            bf16x8 e[ECNT];
            #pragma unroll
            for (int i = 0; i < ECNT; ++i) {
                const int cb = (e_beg + i) * 4 + kg;
                const int cbb = LAYER ? (cb - 128) : cb;
                e[i] = *(const bf16x8*)(ebase + (size_t)cbb * 512 + rowA * 8);
            }
            #pragma unroll
            for (int i = 0; i < ECNT; ++i) {
                const int ks = e_beg + i;
                const bf16x8 w0 = *(const bf16x8*)(lW + ((size_t)ks * 64 + l) * 8);
                const bf16x8 w1 = *(const bf16x8*)(lW + ((size_t)(KST + ks) * 64 + l) * 8);
                acc0 = __builtin_amdgcn_mfma_f32_16x16x32_bf16(e[i], w0, acc0, 0, 0, 0);
                acc1 = __builtin_amdgcn_mfma_f32_16x16x32_bf16(e[i], w1, acc1, 0, 0, 0);
            }
        }

        // ---- late gate: L0 needs flag0[t-1], L1 needs flag0[t]; poller wave 0 ----
        if (LAYER || t > 0) {
            const int tt = LAYER ? t : t - 1;
            const int tgt = LAYER ? t + 1 : t;
            if (wid == 0) {
                wait_flags(flag0 + (size_t)tt * 128, l);
                __hip_atomic_store(&ready[0], tgt, __ATOMIC_RELEASE,
                                   __HIP_MEMORY_SCOPE_WORKGROUP);
            } else {
                lds_spin(&ready[0], tgt);
            }
        }
        asm volatile("" ::: "memory");

        // ---- late phase: L0 = Uh*h0[t-1], L1 = Wx*h0[t]; 16-deep preload ----
        {
            const bfreg* lbase = LAYER ? s0 : s1;     // L1 late: cb ; L0: cb-64
            bf16x8 a[LCNT];
            #pragma unroll
            for (int i = 0; i < LCNT; ++i) {
                const int cb = (l_beg + i) * 4 + kg;
                const int cbb = LAYER ? cb : (cb - 64);
                a[i] = *(const bf16x8*)(lbase + (size_t)cbb * 512 + rowA * 8);
            }
            #pragma unroll
            for (int i = 0; i < LCNT; ++i) {
                const int ks = l_beg + i;
                const bf16x8 w0 = *(const bf16x8*)(lW + ((size_t)ks * 64 + l) * 8);
                const bf16x8 w1 = *(const bf16x8*)(lW + ((size_t)(KST + ks) * 64 + l) * 8);
                acc0 = __builtin_amdgcn_mfma_f32_16x16x32_bf16(a[i], w0, acc0, 0, 0, 0);
                acc1 = __builtin_amdgcn_mfma_f32_16x16x32_bf16(a[i], w1, acc1, 0, 0, 0);
            }
        }

        // C/D: col(rr in ntile) = l&15 ; row(batch) = m*16 + (l>>4)*4 + r
        float* gb = gatebuf + kh * (32 * 68);
        const int bb = m * 16 + (l >> 4) * 4;
        *(f32x4*)(gb + (0 * 16 + cl) * 68 + bb) = acc0;
        *(f32x4*)(gb + (1 * 16 + cl) * 68 + bb) = acc1;
        __syncthreads();   // [A] gates ready (sole per-step WG barrier)

        // ---- epilogue + direct per-wave publish ----
        {
            const int uo = tid & 7, b = tid >> 3;
            float* g0 = gatebuf;
            float* g1 = gatebuf + 32 * 68;
            const float fv = g0[uo * 68 + b]        + g1[uo * 68 + b]        + lbias[uo];
            const float iv = g0[(8 + uo) * 68 + b]  + g1[(8 + uo) * 68 + b]  + lbias[8 + uo];
            const float ov = g0[(16 + uo) * 68 + b] + g1[(16 + uo) * 68 + b] + lbias[16 + uo];
            const float gv = g0[(24 + uo) * 68 + b] + g1[(24 + uo) * 68 + b] + lbias[24 + uo];
            const float c = cbuf[uo * 68 + b];
            const float fg = sigf(fv), ig = sigf(iv), og = sigf(ov);
            const float gg = tanhfast(gv);
            const float cn = fg * c + ig * gg;
            cbuf[uo * 68 + b] = cn;
            const bfreg hv = (bfreg)(og * tanhfast(cn));
            unsigned short hs;
            __builtin_memcpy(&hs, &hv, 2);
            const unsigned hw = hs;
            // thread tid holds slice element tid: per-wave 128B coalesced store
            bfreg* dp = Hme + (size_t)(t + 1) * BH + rg * 512 + tid;
            asm volatile("global_store_short %0, %1, off sc0 sc1"
                         :: "v"(dp), "v"(hw) : "memory");
            asm volatile("s_waitcnt vmcnt(0)" ::: "memory");
        }
        if (l == 0)
            __hip_atomic_fetch_add(done, 1, __ATOMIC_ACQ_REL,
                                   __HIP_MEMORY_SCOPE_WORKGROUP);
        if (wid == 1) {
            // publisher wave: all 8 waves' h stores LLC-acked -> set flag
            while (__hip_atomic_load(done, __ATOMIC_ACQUIRE,
                                     __HIP_MEMORY_SCOPE_WORKGROUP) < 8 * (t + 1)) {}
            if (l == 0) {
                unsigned* fp = myflag + (size_t)t * 128;
                const unsigned one = 1u;
                asm volatile("global_store_dword %0, %1, off sc0 sc1"
                             :: "v"(fp), "v"(one) : "memory");
            }
        }
    }
}

__global__ __launch_bounds__(THREADS, 1)
void lstm_scan(const bfreg* __restrict__ Pw0, const bfreg* __restrict__ Pw1,
               const float* __restrict__ bias0, const float* __restrict__ bias1,
               const bfreg* __restrict__ x_pk,
               bfreg* __restrict__ Hb0, bfreg* __restrict__ Hb1,
               unsigned* __restrict__ flag0, unsigned* __restrict__ flag1)
{
    extern __shared__ char smem[];
    const int wgid = blockIdx.x;
    const int rg = wgid >> 1;
    if (wgid & 1)
        scan_layer<1>(Pw1, bias1, x_pk, Hb0, Hb1, flag0, flag1, rg, smem);
    else
        scan_layer<0>(Pw0, bias0, x_pk, Hb0, Hb1, flag0, flag1, rg, smem);
}

// ---------- FC head ----------
// A = Hb1 slots 1..512 in chunked layout; Wb row-major [OUT][HDIM]
__global__ void fc_gemm(const bfreg* __restrict__ Hb1, const bfreg* __restrict__ Wb,
                        const float* __restrict__ bias, float* __restrict__ out)
{
    const int lane = threadIdx.x & 63;
    const int wid = threadIdx.x >> 6;
    const int cl = lane & 15, kg = lane >> 4;
    const int mbase = blockIdx.y * 64 + (wid >> 1) * 32;
    const int nbase = blockIdx.x * 64 + (wid & 1) * 32;
    const int t = mbase >> 6;
    const int b0 = mbase & 63;
    const bfreg* pa0 = Hb1 + (size_t)(t + 1) * BH + (size_t)kg * 512 + (b0 + cl) * 8;
    const bfreg* pa1 = pa0 + 16 * 8;
    const bfreg* pb0 = Wb + (size_t)(nbase + cl) * HDIM + kg * 8;
    const bfreg* pb1 = pb0 + (size_t)16 * HDIM;
    f32x4 acc[2][2] = {};
    #pragma unroll 4
    for (int k = 0; k < HDIM; k += 32) {
        const size_t co = (size_t)(k >> 3) * 512;
        const bf16x8 av0 = *(const bf16x8*)(pa0 + co);
        const bf16x8 av1 = *(const bf16x8*)(pa1 + co);
        const bf16x8 bv0 = *(const bf16x8*)(pb0 + k);
        const bf16x8 bv1 = *(const bf16x8*)(pb1 + k);
        acc[0][0] = __builtin_amdgcn_mfma_f32_16x16x32_bf16(av0, bv0, acc[0][0], 0, 0, 0);
        acc[0][1] = __builtin_amdgcn_mfma_f32_16x16x32_bf16(av0, bv1, acc[0][1], 0, 0, 0);
        acc[1][0] = __builtin_amdgcn_mfma_f32_16x16x32_bf16(av1, bv0, acc[1][0], 0, 0, 0);
        acc[1][1] = __builtin_amdgcn_mfma_f32_16x16x32_bf16(av1, bv1, acc[1][1], 0, 0, 0);
    }
    #pragma unroll
    for (int mi = 0; mi < 2; ++mi)
        #pragma unroll
        for (int ni = 0; ni < 2; ++ni)
            #pragma unroll
            for (int r = 0; r < 4; ++r) {
                const int row = mbase + mi * 16 + kg * 4 + r;
                const int col = nbase + ni * 16 + cl;
                out[(size_t)row * OUTDIM + col] = acc[mi][ni][r] + bias[col];
            }
}

extern "C" void kernel_launch(void* const* d_in, const int* in_sizes, int n_in,
                              void* d_out, int out_size, void* d_ws, size_t ws_size,
                              hipStream_t stream)
{
    const float* x     = (const float*)d_in[0];
    const float* l0_Wx = (const float*)d_in[1];
    const float* l0_Uh = (const float*)d_in[2];
    const float* l0_bx = (const float*)d_in[3];
    const float* l0_bh = (const float*)d_in[4];
    const float* l1_Wx = (const float*)d_in[5];
    const float* l1_Uh = (const float*)d_in[6];
    const float* l1_bx = (const float*)d_in[7];
    const float* l1_bh = (const float*)d_in[8];
    const float* fc_W  = (const float*)d_in[9];
    const float* fc_b  = (const float*)d_in[10];
    (void)in_sizes; (void)n_in; (void)out_size; (void)ws_size;

    char* p = (char*)d_ws;
    size_t off = 0;
    auto take = [&](size_t bytes) {
        void* r = p + off;
        off = (off + bytes + 255) & ~(size_t)255;
        return r;
    };

    bfreg* x_pk  = (bfreg*)take((size_t)SDIM * BDIM * INDIM * 2);
    bfreg* Pw0   = (bfreg*)take((size_t)128 * 48 * 1024 * 2);
    bfreg* Pw1   = (bfreg*)take((size_t)128 * 64 * 1024 * 2);
    bfreg* fcWb  = (bfreg*)take((size_t)OUTDIM * HDIM * 2);
    float* bias0 = (float*)take((size_t)4 * HDIM * 4);
    float* bias1 = (float*)take((size_t)4 * HDIM * 4);
    bfreg* Hb0   = (bfreg*)take((size_t)(SDIM + 1) * BH * 2);
    bfreg* Hb1   = (bfreg*)take((size_t)(SDIM + 1) * BH * 2);
    unsigned* flag0 = (unsigned*)take((size_t)SDIM * 128 * 4);
    unsigned* flag1 = (unsigned*)take((size_t)SDIM * 128 * 4);

    // deterministic per-call init (graph-replayed)
    hipMemsetAsync(Hb0, 0, (size_t)BH * 2, stream);
    hipMemsetAsync(Hb1, 0, (size_t)BH * 2, stream);
    hipMemsetAsync(flag0, 0, (size_t)SDIM * 128 * 4, stream);
    hipMemsetAsync(flag1, 0, (size_t)SDIM * 128 * 4, stream);

    pack_x<<<4096, 256, 0, stream>>>(x_pk, x);
    cvt_bf16<<<512, 256, 0, stream>>>(fcWb, fc_W, OUTDIM * HDIM / 4);
    pack_w<<<3072, 256, 0, stream>>>(Pw0, l0_Wx, l0_Uh, INDIM, HDIM);
    pack_w<<<4096, 256, 0, stream>>>(Pw1, l1_Wx, l1_Uh, HDIM, HDIM);
    bias_combine<<<16, 256, 0, stream>>>(bias0, l0_bx, l0_bh, bias1, l1_bx, l1_bh);

    const int smem_bytes = 64 * 2048 + 2 * 32 * 68 * 4 + 8 * 68 * 4 + 32 * 4 + 16;
    hipFuncSetAttribute((const void*)lstm_scan,
                        hipFuncAttributeMaxDynamicSharedMemorySize, smem_bytes);
    lstm_scan<<<NWG, THREADS, smem_bytes, stream>>>(Pw0, Pw1, bias0, bias1,
                                                    x_pk, Hb0, Hb1, flag0, flag1);

    fc_gemm<<<dim3(OUTDIM / 64, SDIM * BDIM / 64), 256, 0, stream>>>(
        Hb1, fcWb, fc_b, (float*)d_out);
}

// Round 7
// 4411.622 us; speedup vs baseline: 1.5526x; 1.0198x over previous
//
#include <hip/hip_runtime.h>
#include <hip/hip_bf16.h>

#define SDIM 512
#define BDIM 64
#define INDIM 512
#define HDIM 1024
#define OUTDIM 512
#define NWG 256
#define THREADS 512
#define BH (BDIM * HDIM)

typedef __bf16 bfreg;
typedef bfreg bf16x8 __attribute__((ext_vector_type(8)));
typedef bfreg bf16x4 __attribute__((ext_vector_type(4)));
typedef float f32x4 __attribute__((ext_vector_type(4)));

__device__ __forceinline__ float sigf(float x) { return 1.f / (1.f + __expf(-x)); }
__device__ __forceinline__ float tanhfast(float x) { return 1.f - 2.f / (__expf(2.f * x) + 1.f); }

// ---------- preamble kernels ----------

__global__ void cvt_bf16(bfreg* __restrict__ dst, const float* __restrict__ src, int n4)
{
    for (int i = blockIdx.x * blockDim.x + threadIdx.x; i < n4; i += gridDim.x * blockDim.x) {
        const float4 v = *(const float4*)(src + (size_t)i * 4);
        bf16x4 o;
        o[0] = (bfreg)v.x; o[1] = (bfreg)v.y; o[2] = (bfreg)v.z; o[3] = (bfreg)v.w;
        *(bf16x4*)(dst + (size_t)i * 4) = o;
    }
}

__global__ void bias_combine(float* __restrict__ b0, const float* __restrict__ bx0,
                             const float* __restrict__ bh0,
                             float* __restrict__ b1, const float* __restrict__ bx1,
                             const float* __restrict__ bh1)
{
    int i = blockIdx.x * blockDim.x + threadIdx.x;
    if (i < 4 * HDIM) {
        b0[i] = bx0[i] + bh0[i];
        b1[i] = bx1[i] + bh1[i];
    }
}

// Pack x [S][B][IN] fp32 -> chunked bf16 [S][IN/8][B][8]
__global__ void pack_x(bfreg* __restrict__ dst, const float* __restrict__ src)
{
    const int total = SDIM * (INDIM / 8) * BDIM;      // 16B chunks
    for (int idx = blockIdx.x * blockDim.x + threadIdx.x; idx < total;
         idx += gridDim.x * blockDim.x) {
        const int b = idx & (BDIM - 1);
        const int r = idx >> 6;
        const int kb = r & (INDIM / 8 - 1);
        const int t = r >> 6;
        const float* s = src + ((size_t)t * BDIM + b) * INDIM + kb * 8;
        bfreg* d = dst + (size_t)idx * 8;
        #pragma unroll
        for (int j = 0; j < 8; ++j) d[j] = (bfreg)s[j];
    }
}

// Pack W = [Wx | Uh] (row-major fp32) into per-WG MFMA B-fragment order, bf16.
// dst chunk idx = ((wg*2 + nt)*KST + ks)*64 + lane ; each chunk = 8 bf16.
// rr = nt*16 + (lane&15); g = rr>>3, uo = rr&7; row = g*HDIM + wg*8 + uo;
// k = ks*32 + (lane>>4)*8 + j.
__global__ void pack_w(bfreg* __restrict__ dst, const float* __restrict__ Wx,
                       const float* __restrict__ Uh, int K0, int KH)
{
    const int KST = (K0 + KH) / 32;
    const int total = 128 * 2 * KST * 64;
    for (int idx = blockIdx.x * blockDim.x + threadIdx.x; idx < total;
         idx += gridDim.x * blockDim.x) {
        const int lane = idx & 63;
        int rem = idx >> 6;
        const int ks = rem % KST; rem /= KST;
        const int nt = rem & 1;
        const int wg = rem >> 1;
        const int rr = nt * 16 + (lane & 15);
        const int g = rr >> 3, uo = rr & 7;
        const int row = g * HDIM + wg * 8 + uo;
        const int k = ks * 32 + (lane >> 4) * 8;
        const float* s = (k < K0) ? Wx + (size_t)row * K0 + k
                                  : Uh + (size_t)row * KH + (k - K0);
        bfreg* d = dst + (size_t)idx * 8;
        #pragma unroll
        for (int j = 0; j < 8; ++j) d[j] = (bfreg)s[j];
    }
}

// ---------- sync helpers ----------
// per-(layer,step) counter, 64B padded: producers atomic-add 1; consumers
// poll a single dword (same-address across lanes -> one LLC request/round).

__device__ __forceinline__ void wait_cnt(const unsigned* c)
{
    while (__hip_atomic_load(c, __ATOMIC_RELAXED, __HIP_MEMORY_SCOPE_AGENT) < 128u)
        __builtin_amdgcn_s_sleep(1);
}

__device__ __forceinline__ void lds_spin(int* r, int target)
{
    while (__hip_atomic_load(r, __ATOMIC_ACQUIRE, __HIP_MEMORY_SCOPE_WORKGROUP) < target)
        __builtin_amdgcn_s_sleep(1);
}

// ---------- persistent 2-layer LSTM scan: two-phase waves ----------
// 256 WGs x 512 threads, 1 WG/CU. layer = wgid&1, rg = wgid>>1 (8 h-units,
// 32 gate rows). Waves: wid = (kh<<2)|m ; m = 16-row batch tile, kh = K-half
// of EACH phase. Per step each wave does:
//   EARLY (weak/no gate):  L0: x chunks        L1: Uh1*h1[t-1]   (8/16 iters)
//   LATE  (flag-gated):    L0: Uh0*h0[t-1]     L1: Wx1*h0[t]     (16 iters)
// accumulated into the same registers; late A-frags preloaded 16-deep.
// Pollers: wave0 = late gate (cnt0); wave4 = L1 early gate (cnt1);
// wave1 = publisher (spins LDS done counter, then one atomic add).
template<int LAYER>
__device__ __forceinline__ void scan_layer(
    const bfreg* __restrict__ Pw, const float* __restrict__ biasL,
    const bfreg* __restrict__ x_pk,
    bfreg* __restrict__ Hb0, bfreg* __restrict__ Hb1,
    unsigned* __restrict__ cnt0, unsigned* __restrict__ cnt1,
    const int rg, char* smem)
{
    constexpr int KST = LAYER ? 64 : 48;
    constexpr int ECNT = LAYER ? 16 : 8;
    constexpr int LCNT = 16;

    const int tid = threadIdx.x;
    const int l = tid & 63;
    const int wid = tid >> 6;
    const int m = wid & 3;
    const int kh = wid >> 2;

    bfreg* lW = (bfreg*)smem;
    float* gatebuf = (float*)(smem + 64 * 2048);   // [2][32][68]
    float* cbuf = gatebuf + 2 * 32 * 68;           // [8][68]
    float* lbias = cbuf + 8 * 68;                  // [32]
    int* ready = (int*)(lbias + 32);               // [0],[1] gates, [2] done

    // stage packed weights (once)
    {
        const float4* wsrc = (const float4*)(Pw + (size_t)rg * ((size_t)KST * 1024));
        float4* wdst = (float4*)lW;
        for (int i = tid; i < KST * 128; i += THREADS) wdst[i] = wsrc[i];
    }
    if (tid < 32) lbias[tid] = biasL[(tid >> 3) * HDIM + rg * 8 + (tid & 7)];
    if (tid < 3) ready[tid] = 0;
    for (int i = tid; i < 8 * 68; i += THREADS) cbuf[i] = 0.f;
    __syncthreads();

    const int cl = l & 15, kg = l >> 4;
    const int rowA = m * 16 + cl;
    const int e_beg = LAYER ? (32 + kh * 16) : (kh * 8);
    const int l_beg = LAYER ? (kh * 16) : (16 + kh * 16);

    unsigned* mycnt = LAYER ? cnt1 : cnt0;
    bfreg* Hme = LAYER ? Hb1 : Hb0;
    int* done = ready + 2;

    for (int t = 0; t < SDIM; ++t) {
        // ---- early gate (L1 only): cnt1[t-1], poller = wave 4 ----
        if (LAYER && t > 0) {
            if (wid == 4) {
                wait_cnt(cnt1 + (size_t)(t - 1) * 16);
                __hip_atomic_store(&ready[1], t, __ATOMIC_RELEASE,
                                   __HIP_MEMORY_SCOPE_WORKGROUP);
            } else {
                lds_spin(&ready[1], t);
            }
        }
        asm volatile("" ::: "memory");

        const bfreg* s0 = LAYER ? Hb0 + (size_t)(t + 1) * BH
                                : x_pk + (size_t)t * (64 * BDIM * 8);
        const bfreg* s1 = LAYER ? Hb1 + (size_t)t * BH
                                : Hb0 + (size_t)t * BH;

        f32x4 acc0 = {0.f, 0.f, 0.f, 0.f};
        f32x4 acc1 = {0.f, 0.f, 0.f, 0.f};

        // ---- early phase: L0 = Wx*x[t] (no gate), L1 = Uh*h1[t-1] ----
        {
            const bfreg* ebase = LAYER ? s1 : s0;     // L1 early: cb-128 ; L0: cb
            bf16x8 e[ECNT];
            #pragma unroll
            for (int i = 0; i < ECNT; ++i) {
                const int cb = (e_beg + i) * 4 + kg;
                const int cbb = LAYER ? (cb - 128) : cb;
                e[i] = *(const bf16x8*)(ebase + (size_t)cbb * 512 + rowA * 8);
            }
            #pragma unroll
            for (int i = 0; i < ECNT; ++i) {
                const int ks = e_beg + i;
                const bf16x8 w0 = *(const bf16x8*)(lW + ((size_t)ks * 64 + l) * 8);
                const bf16x8 w1 = *(const bf16x8*)(lW + ((size_t)(KST + ks) * 64 + l) * 8);
                acc0 = __builtin_amdgcn_mfma_f32_16x16x32_bf16(e[i], w0, acc0, 0, 0, 0);
                acc1 = __builtin_amdgcn_mfma_f32_16x16x32_bf16(e[i], w1, acc1, 0, 0, 0);
            }
        }

        // ---- late gate: L0 needs cnt0[t-1], L1 needs cnt0[t]; poller wave 0 ----
        if (LAYER || t > 0) {
            const int tt = LAYER ? t : t - 1;
            const int tgt = LAYER ? t + 1 : t;
            if (wid == 0) {
                wait_cnt(cnt0 + (size_t)tt * 16);
                __hip_atomic_store(&ready[0], tgt, __ATOMIC_RELEASE,
                                   __HIP_MEMORY_SCOPE_WORKGROUP);
            } else {
                lds_spin(&ready[0], tgt);
            }
        }
        asm volatile("" ::: "memory");

        // ---- late phase: L0 = Uh*h0[t-1], L1 = Wx*h0[t]; 16-deep preload ----
        {
            const bfreg* lbase = LAYER ? s0 : s1;     // L1 late: cb ; L0: cb-64
            bf16x8 a[LCNT];
            #pragma unroll
            for (int i = 0; i < LCNT; ++i) {
                const int cb = (l_beg + i) * 4 + kg;
                const int cbb = LAYER ? cb : (cb - 64);
                a[i] = *(const bf16x8*)(lbase + (size_t)cbb * 512 + rowA * 8);
            }
            #pragma unroll
            for (int i = 0; i < LCNT; ++i) {
                const int ks = l_beg + i;
                const bf16x8 w0 = *(const bf16x8*)(lW + ((size_t)ks * 64 + l) * 8);
                const bf16x8 w1 = *(const bf16x8*)(lW + ((size_t)(KST + ks) * 64 + l) * 8);
                acc0 = __builtin_amdgcn_mfma_f32_16x16x32_bf16(a[i], w0, acc0, 0, 0, 0);
                acc1 = __builtin_amdgcn_mfma_f32_16x16x32_bf16(a[i], w1, acc1, 0, 0, 0);
            }
        }

        // C/D: col(rr in ntile) = l&15 ; row(batch) = m*16 + (l>>4)*4 + r
        float* gb = gatebuf + kh * (32 * 68);
        const int bb = m * 16 + (l >> 4) * 4;
        *(f32x4*)(gb + (0 * 16 + cl) * 68 + bb) = acc0;
        *(f32x4*)(gb + (1 * 16 + cl) * 68 + bb) = acc1;
        __syncthreads();   // [A] gates ready (sole per-step WG barrier)

        // ---- epilogue + direct per-wave publish ----
        {
            const int uo = tid & 7, b = tid >> 3;
            float* g0 = gatebuf;
            float* g1 = gatebuf + 32 * 68;
            const float fv = g0[uo * 68 + b]        + g1[uo * 68 + b]        + lbias[uo];
            const float iv = g0[(8 + uo) * 68 + b]  + g1[(8 + uo) * 68 + b]  + lbias[8 + uo];
            const float ov = g0[(16 + uo) * 68 + b] + g1[(16 + uo) * 68 + b] + lbias[16 + uo];
            const float gv = g0[(24 + uo) * 68 + b] + g1[(24 + uo) * 68 + b] + lbias[24 + uo];
            const float c = cbuf[uo * 68 + b];
            const float fg = sigf(fv), ig = sigf(iv), og = sigf(ov);
            const float gg = tanhfast(gv);
            const float cn = fg * c + ig * gg;
            cbuf[uo * 68 + b] = cn;
            const bfreg hv = (bfreg)(og * tanhfast(cn));
            unsigned short hs;
            __builtin_memcpy(&hs, &hv, 2);
            const unsigned hw = hs;
            // thread tid holds slice element tid: per-wave 128B coalesced store
            bfreg* dp = Hme + (size_t)(t + 1) * BH + rg * 512 + tid;
            asm volatile("global_store_short %0, %1, off sc0 sc1"
                         :: "v"(dp), "v"(hw) : "memory");
            asm volatile("s_waitcnt vmcnt(0)" ::: "memory");
        }
        if (l == 0)
            __hip_atomic_fetch_add(done, 1, __ATOMIC_ACQ_REL,
                                   __HIP_MEMORY_SCOPE_WORKGROUP);
        if (wid == 1) {
            // publisher wave: all 8 waves' h stores LLC-acked -> count this WG
            while (__hip_atomic_load(done, __ATOMIC_ACQUIRE,
                                     __HIP_MEMORY_SCOPE_WORKGROUP) < 8 * (t + 1))
                __builtin_amdgcn_s_sleep(1);
            if (l == 0)
                __hip_atomic_fetch_add(mycnt + (size_t)t * 16, 1u,
                                       __ATOMIC_RELAXED, __HIP_MEMORY_SCOPE_AGENT);
        }
    }
}

__global__ __launch_bounds__(THREADS, 1)
void lstm_scan(const bfreg* __restrict__ Pw0, const bfreg* __restrict__ Pw1,
               const float* __restrict__ bias0, const float* __restrict__ bias1,
               const bfreg* __restrict__ x_pk,
               bfreg* __restrict__ Hb0, bfreg* __restrict__ Hb1,
               unsigned* __restrict__ cnt0, unsigned* __restrict__ cnt1)
{
    extern __shared__ char smem[];
    const int wgid = blockIdx.x;
    const int rg = wgid >> 1;
    if (wgid & 1)
        scan_layer<1>(Pw1, bias1, x_pk, Hb0, Hb1, cnt0, cnt1, rg, smem);
    else
        scan_layer<0>(Pw0, bias0, x_pk, Hb0, Hb1, cnt0, cnt1, rg, smem);
}

// ---------- FC head ----------
// A = Hb1 slots 1..512 in chunked layout; Wb row-major [OUT][HDIM]
__global__ void fc_gemm(const bfreg* __restrict__ Hb1, const bfreg* __restrict__ Wb,
                        const float* __restrict__ bias, float* __restrict__ out)
{
    const int lane = threadIdx.x & 63;
    const int wid = threadIdx.x >> 6;
    const int cl = lane & 15, kg = lane >> 4;
    const int mbase = blockIdx.y * 64 + (wid >> 1) * 32;
    const int nbase = blockIdx.x * 64 + (wid & 1) * 32;
    const int t = mbase >> 6;
    const int b0 = mbase & 63;
    const bfreg* pa0 = Hb1 + (size_t)(t + 1) * BH + (size_t)kg * 512 + (b0 + cl) * 8;
    const bfreg* pa1 = pa0 + 16 * 8;
    const bfreg* pb0 = Wb + (size_t)(nbase + cl) * HDIM + kg * 8;
    const bfreg* pb1 = pb0 + (size_t)16 * HDIM;
    f32x4 acc[2][2] = {};
    #pragma unroll 4
    for (int k = 0; k < HDIM; k += 32) {
        const size_t co = (size_t)(k >> 3) * 512;
        const bf16x8 av0 = *(const bf16x8*)(pa0 + co);
        const bf16x8 av1 = *(const bf16x8*)(pa1 + co);
        const bf16x8 bv0 = *(const bf16x8*)(pb0 + k);
        const bf16x8 bv1 = *(const bf16x8*)(pb1 + k);
        acc[0][0] = __builtin_amdgcn_mfma_f32_16x16x32_bf16(av0, bv0, acc[0][0], 0, 0, 0);
        acc[0][1] = __builtin_amdgcn_mfma_f32_16x16x32_bf16(av0, bv1, acc[0][1], 0, 0, 0);
        acc[1][0] = __builtin_amdgcn_mfma_f32_16x16x32_bf16(av1, bv0, acc[1][0], 0, 0, 0);
        acc[1][1] = __builtin_amdgcn_mfma_f32_16x16x32_bf16(av1, bv1, acc[1][1], 0, 0, 0);
    }
    #pragma unroll
    for (int mi = 0; mi < 2; ++mi)
        #pragma unroll
        for (int ni = 0; ni < 2; ++ni)
            #pragma unroll
            for (int r = 0; r < 4; ++r) {
                const int row = mbase + mi * 16 + kg * 4 + r;
                const int col = nbase + ni * 16 + cl;
                out[(size_t)row * OUTDIM + col] = acc[mi][ni][r] + bias[col];
            }
}

extern "C" void kernel_launch(void* const* d_in, const int* in_sizes, int n_in,
                              void* d_out, int out_size, void* d_ws, size_t ws_size,
                              hipStream_t stream)
{
    const float* x     = (const float*)d_in[0];
    const float* l0_Wx = (const float*)d_in[1];
    const float* l0_Uh = (const float*)d_in[2];
    const float* l0_bx = (const float*)d_in[3];
    const float* l0_bh = (const float*)d_in[4];
    const float* l1_Wx = (const float*)d_in[5];
    const float* l1_Uh = (const float*)d_in[6];
    const float* l1_bx = (const float*)d_in[7];
    const float* l1_bh = (const float*)d_in[8];
    const float* fc_W  = (const float*)d_in[9];
    const float* fc_b  = (const float*)d_in[10];
    (void)in_sizes; (void)n_in; (void)out_size; (void)ws_size;

    char* p = (char*)d_ws;
    size_t off = 0;
    auto take = [&](size_t bytes) {
        void* r = p + off;
        off = (off + bytes + 255) & ~(size_t)255;
        return r;
    };

    bfreg* x_pk  = (bfreg*)take((size_t)SDIM * BDIM * INDIM * 2);
    bfreg* Pw0   = (bfreg*)take((size_t)128 * 48 * 1024 * 2);
    bfreg* Pw1   = (bfreg*)take((size_t)128 * 64 * 1024 * 2);
    bfreg* fcWb  = (bfreg*)take((size_t)OUTDIM * HDIM * 2);
    float* bias0 = (float*)take((size_t)4 * HDIM * 4);
    float* bias1 = (float*)take((size_t)4 * HDIM * 4);
    bfreg* Hb0   = (bfreg*)take((size_t)(SDIM + 1) * BH * 2);
    bfreg* Hb1   = (bfreg*)take((size_t)(SDIM + 1) * BH * 2);
    unsigned* cnt0 = (unsigned*)take((size_t)SDIM * 16 * 4);   // 64B-padded counters
    unsigned* cnt1 = (unsigned*)take((size_t)SDIM * 16 * 4);

    // deterministic per-call init (graph-replayed)
    hipMemsetAsync(Hb0, 0, (size_t)BH * 2, stream);
    hipMemsetAsync(Hb1, 0, (size_t)BH * 2, stream);
    hipMemsetAsync(cnt0, 0, (size_t)SDIM * 16 * 4, stream);
    hipMemsetAsync(cnt1, 0, (size_t)SDIM * 16 * 4, stream);

    pack_x<<<4096, 256, 0, stream>>>(x_pk, x);
    cvt_bf16<<<512, 256, 0, stream>>>(fcWb, fc_W, OUTDIM * HDIM / 4);
    pack_w<<<3072, 256, 0, stream>>>(Pw0, l0_Wx, l0_Uh, INDIM, HDIM);
    pack_w<<<4096, 256, 0, stream>>>(Pw1, l1_Wx, l1_Uh, HDIM, HDIM);
    bias_combine<<<16, 256, 0, stream>>>(bias0, l0_bx, l0_bh, bias1, l1_bx, l1_bh);

    const int smem_bytes = 64 * 2048 + 2 * 32 * 68 * 4 + 8 * 68 * 4 + 32 * 4 + 16;
    hipFuncSetAttribute((const void*)lstm_scan,
                        hipFuncAttributeMaxDynamicSharedMemorySize, smem_bytes);
    lstm_scan<<<NWG, THREADS, smem_bytes, stream>>>(Pw0, Pw1, bias0, bias1,
                                                    x_pk, Hb0, Hb1, cnt0, cnt1);

    fc_gemm<<<dim3(OUTDIM / 64, SDIM * BDIM / 64), 256, 0, stream>>>(
        Hb1, fcWb, fc_b, (float*)d_out);
}